// Round 5
// baseline (389.487 us; speedup 1.0000x reference)
//
#include <hip/hip_runtime.h>

#define BB 4
#define NN 16384
#define SS 4096
#define CC 256
#define KBINS 128
#define QBINS 512
#define QCH 32       // queries per scan block
#define TILE_LD 260  // padded leading dim for out-transpose tile

// ---- ws layout (bytes) ----
// [0)      kcnt   4*128 ints (2 KB)
// [2048)   qcnt   4*512 ints (8 KB)          -> zeroed region ends 10240
// [10240)  koff   512 ints
// [12288)  kcur   512 ints
// [14336)  qcur   2048 ints (ends 22528)
// [32768)  ksort  float4[4*4096] (ends 294912)
// [294912) kidx   int[4*4096]    (ends 360448)
// [393216) qsort  int[4*16384]   (ends 655360)   <- moved: was overlapping kidx!
// [1 MB)   idx_out int4[65536]   (1 MB)
// [2 MB)   w_out  float4[65536]  (1 MB)
#define WS_ZERO_BYTES 10240

__device__ __forceinline__ int kbin_of(float z) {
  float t = (z + 5.0f) * 12.8f;  // 128 bins over [-5,5]
  t = fminf(fmaxf(t, 0.0f), 127.0f);
  return (int)t;
}
__device__ __forceinline__ int qbin_of(float z) {
  float t = (z + 5.0f) * 51.2f;  // 512 bins over [-5,5]
  t = fminf(fmaxf(t, 0.0f), 511.0f);
  return (int)t;
}

#define LEXLT(da, ia, db, ib) (((da) < (db)) || (((da) == (db)) && ((ia) < (ib))))

// order-agnostic lex insert of (d,s) into sorted (D0,I0)<=(D1,I1)<=(D2,I2)
#define LEX_INSERT(d, s)                                   \
  do {                                                     \
    bool b2_ = LEXLT(d, s, D2, I2);                        \
    bool b1_ = LEXLT(d, s, D1, I1);                        \
    bool b0_ = LEXLT(d, s, D0, I0);                        \
    I2 = b1_ ? I1 : (b2_ ? (s) : I2);                      \
    I1 = b0_ ? I0 : (b1_ ? (s) : I1);                      \
    I0 = b0_ ? (s) : I0;                                   \
    float nd2_ = __builtin_amdgcn_fmed3f((d), D1, D2);     \
    float nd1_ = __builtin_amdgcn_fmed3f((d), D0, D1);     \
    D0 = fminf((d), D0);                                   \
    D2 = nd2_; D1 = nd1_;                                  \
  } while (0)

// ---------------- build kernels ----------------
__global__ __launch_bounds__(256) void count_kernel(const float* __restrict__ qg,
                                                    const float* __restrict__ kg,
                                                    int* __restrict__ ws) {
  int gid = blockIdx.x * 256 + threadIdx.x;
  int* kcnt = ws;
  int* qcnt = ws + 512;
  if (gid < BB * SS) {
    int b = gid >> 12;
    float z = kg[(size_t)gid * 3 + 2];
    atomicAdd(&kcnt[b * KBINS + kbin_of(z)], 1);
  } else if (gid < BB * SS + BB * NN) {
    int q = gid - BB * SS;
    int b = q >> 14;
    float z = qg[(size_t)q * 3 + 2];
    atomicAdd(&qcnt[b * QBINS + qbin_of(z)], 1);
  }
}

__global__ void prefix_kernel(int* __restrict__ ws) {
  int t = threadIdx.x;
  int* kcnt = ws;
  int* qcnt = ws + 512;
  int* koff = ws + 2560;
  int* kcur = ws + 3072;
  int* qcur = ws + 3584;
  if (t < 4) {
    int run = 0;
    for (int i = 0; i < KBINS; ++i) {
      koff[t * KBINS + i] = run;
      kcur[t * KBINS + i] = run;
      run += kcnt[t * KBINS + i];
    }
  } else if (t < 8) {
    int b = t - 4;
    int run = 0;
    for (int i = 0; i < QBINS; ++i) {
      qcur[b * QBINS + i] = run;
      run += qcnt[b * QBINS + i];
    }
  }
}

__global__ __launch_bounds__(256) void scatter_kernel(const float* __restrict__ qg,
                                                      const float* __restrict__ kg,
                                                      int* __restrict__ ws,
                                                      float4* __restrict__ ksort,
                                                      int* __restrict__ kidx,
                                                      int* __restrict__ qsort) {
#pragma clang fp contract(off)
  int gid = blockIdx.x * 256 + threadIdx.x;
  int* kcur = ws + 3072;
  int* qcur = ws + 3584;
  if (gid < BB * SS) {
    int b = gid >> 12, i = gid & (SS - 1);
    float x = kg[(size_t)gid * 3], y = kg[(size_t)gid * 3 + 1], z = kg[(size_t)gid * 3 + 2];
    float kk = (x * x + y * y) + z * z;  // exact np order
    int pos = atomicAdd(&kcur[b * KBINS + kbin_of(z)], 1);
    ksort[(size_t)b * SS + pos] = make_float4(x, y, z, kk);
    kidx[(size_t)b * SS + pos] = i;
  } else if (gid < BB * SS + BB * NN) {
    int q = gid - BB * SS;
    int b = q >> 14, n = q & (NN - 1);
    float z = qg[(size_t)q * 3 + 2];
    int pos = atomicAdd(&qcur[b * QBINS + qbin_of(z)], 1);
    qsort[(size_t)b * NN + pos] = n;
  }
}

// ---------------- scan: z-pruned exact top-3 ----------------
// Grid 2048 = b(4) x chunk(512); 256 threads; 32 z-sorted queries x 8 s-groups.
__global__ __launch_bounds__(256, 8) void scan_kernel(
    const float* __restrict__ qg, const int* __restrict__ ws,
    const float4* __restrict__ ksort, const int* __restrict__ kidx,
    const int* __restrict__ qsort, int4* __restrict__ idx_out,
    float4* __restrict__ w_out) {
#pragma clang fp contract(off)
  __shared__ __align__(16) float4 pts[256];  // 4 KB staged candidates
  __shared__ int pidx[256];
  __shared__ float qs[QCH][4];  // x,y,z,qq
  __shared__ int qidl[QCH];
  __shared__ float red[4];
  __shared__ float bcast[4];  // [0]=maxD2, [1]=zmin, [2]=zmax
  __shared__ float md[7][QCH][3];
  __shared__ int mi[7][QCH][3];

  const int tid = threadIdx.x;
  const int bb = blockIdx.x >> 9;
  const int chunk = blockIdx.x & 511;
  const int qi = tid & 31;
  const int g = tid >> 5;  // 8 groups

  const int* kcnt = ws;
  const int* koff = ws + 2560;
  const float4* ksb = ksort + (size_t)bb * SS;
  const int* kib = kidx + (size_t)bb * SS;

  // stage this block's 32 queries
  if (tid < QCH) {
    int n = qsort[(size_t)bb * NN + chunk * QCH + tid];
    qidl[tid] = n;
    const float* qp = qg + ((size_t)bb * NN + n) * 3;
    float x = qp[0], y = qp[1], z = qp[2];
    qs[tid][0] = x; qs[tid][1] = y; qs[tid][2] = z;
    qs[tid][3] = (x * x + y * y) + z * z;  // exact np order
  }
  __syncthreads();
  if (tid == 0) {
    float zn = 3.0e38f, zx = -3.0e38f;
    for (int i = 0; i < QCH; ++i) {
      float z = qs[i][2];
      zn = fminf(zn, z); zx = fmaxf(zx, z);
    }
    bcast[0] = 3.4e38f; bcast[1] = zn; bcast[2] = zx;
  }
  __syncthreads();

  const float qx = qs[qi][0], qy = qs[qi][1], qz = qs[qi][2], qq = qs[qi][3];
  float D0 = 3.4e38f, D1 = 3.4e38f, D2 = 3.4e38f;
  int I0 = 0, I1 = 0, I2 = 0;

  const float zmin = bcast[1], zmax = bcast[2];
  float maxD2 = bcast[0];

  int ctr = (int)fminf(fmaxf((0.5f * (zmin + zmax) + 5.0f) * 12.8f, 0.0f), 127.0f);
  int bd = ctr, bu = ctr + 1;
  bool ad = true, au = (bu < KBINS);

  while (ad || au) {
    // direction gaps from bin edges (end bins open-ended)
    float hi_d = (bd >= KBINS - 1) ? 3.0e38f : (-5.0f + (float)(bd + 1) * 0.078125f);
    float gd = ad ? fmaxf(zmin - hi_d, 0.0f) : 3.0e38f;
    float lo_u = (bu <= 0) ? -3.0e38f : (-5.0f + (float)bu * 0.078125f);
    float gu = au ? fmaxf(lo_u - zmax, 0.0f) : 3.0e38f;
    bool pickd = ad && (!au || (gd <= gu));
    int b = pickd ? bd : bu;
    float gsel = pickd ? gd : gu;
    if (gsel * gsel > maxD2 * 1.0001f + 1e-3f) {  // conservative margin >> fp error
      if (pickd) ad = false; else au = false;
      continue;
    }
    int start = koff[bb * KBINS + b];
    int cnt = kcnt[bb * KBINS + b];
    for (int off = 0; off < cnt; off += 256) {
      int m = min(256, cnt - off);
      __syncthreads();  // protect pts from previous readers
      if (tid < m) {
        pts[tid] = ksb[start + off + tid];
        pidx[tid] = kib[start + off + tid];
      }
      __syncthreads();
#pragma unroll 2
      for (int i = g; i < m; i += 8) {
        float4 kp = pts[i];
        int s = pidx[i];
        // exact np: d = (qq - 2*dot) + kk; dot left-to-right; fma of -2*dot exact
        float dot = (qx * kp.x + qy * kp.y) + qz * kp.z;
        float d = __builtin_fmaf(dot, -2.0f, qq) + kp.w;
        LEX_INSERT(d, s);
      }
    }
    // refresh block max d2 (conservative >= every query's merged d2)
    float mx = D2;
#pragma unroll
    for (int o = 1; o < 64; o <<= 1) mx = fmaxf(mx, __shfl_xor(mx, o));
    __syncthreads();
    if ((tid & 63) == 0) red[tid >> 6] = mx;
    __syncthreads();
    if (tid == 0) bcast[0] = fmaxf(fmaxf(red[0], red[1]), fmaxf(red[2], red[3]));
    __syncthreads();
    maxD2 = bcast[0];
    if (pickd) { bd--; if (bd < 0) ad = false; }
    else       { bu++; if (bu >= KBINS) au = false; }
  }

  // merge 8 partials per query (order-agnostic lex inserts)
  __syncthreads();
  if (g > 0) {
    md[g - 1][qi][0] = D0; md[g - 1][qi][1] = D1; md[g - 1][qi][2] = D2;
    mi[g - 1][qi][0] = I0; mi[g - 1][qi][1] = I1; mi[g - 1][qi][2] = I2;
  }
  __syncthreads();
  if (tid < QCH) {
    for (int gg = 0; gg < 7; ++gg) {
#pragma unroll
      for (int r = 0; r < 3; ++r) {
        float d = md[gg][tid][r];
        int s = mi[gg][tid][r];
        LEX_INSERT(d, s);
      }
    }
    float r0 = 1.0f / (D0 + 1e-8f);
    float r1 = 1.0f / (D1 + 1e-8f);
    float r2 = 1.0f / (D2 + 1e-8f);
    float rs = (r0 + r1) + r2;
    size_t gid = (size_t)bb * NN + qidl[tid];
    idx_out[gid] = make_int4(I0, I1, I2, 0);
    w_out[gid] = make_float4(r0 / rs, r1 / rs, r2 / rs, 0.0f);
  }
}

// ---------------- gather + weighted sum + transpose ----------------
// Grid 2048 = b(4) x nblk(512); 32 queries x 256 channels per block; 4 blocks/CU.
__global__ __launch_bounds__(256, 4) void gather_kernel(
    const float* __restrict__ vg, const int4* __restrict__ idx_in,
    const float4* __restrict__ w_in, float* __restrict__ outg) {
#pragma clang fp contract(off)
  __shared__ __align__(16) float tile[32 * TILE_LD];  // 33.28 KB
  __shared__ float sw[32][3];
  __shared__ int si[32][3];

  const int tid = threadIdx.x;
  const int blk = blockIdx.x;
  const int b = blk >> 9;
  const int n0 = (blk & 511) << 5;

  if (tid < 32) {
    size_t gid = (size_t)b * NN + n0 + tid;
    int4 I = idx_in[gid];
    float4 W = w_in[gid];
    si[tid][0] = I.x; si[tid][1] = I.y; si[tid][2] = I.z;
    sw[tid][0] = W.x; sw[tid][1] = W.y; sw[tid][2] = W.z;
  }
  __syncthreads();

  const int wv = tid >> 6;
  const int lane = tid & 63;
  const float* vb = vg + (size_t)b * SS * CC;

#pragma unroll 4
  for (int i = 0; i < 8; ++i) {
    int qs2 = wv * 8 + i;
    float w0 = sw[qs2][0], w1 = sw[qs2][1], w2 = sw[qs2][2];
    const float4* r0p = (const float4*)(vb + (size_t)si[qs2][0] * CC);
    const float4* r1p = (const float4*)(vb + (size_t)si[qs2][1] * CC);
    const float4* r2p = (const float4*)(vb + (size_t)si[qs2][2] * CC);
    float4 a0 = r0p[lane], a1 = r1p[lane], a2 = r2p[lane];
    float4 acc;
    acc.x = (w0 * a0.x + w1 * a1.x) + w2 * a2.x;
    acc.y = (w0 * a0.y + w1 * a1.y) + w2 * a2.y;
    acc.z = (w0 * a0.z + w1 * a1.z) + w2 * a2.z;
    acc.w = (w0 * a0.w + w1 * a1.w) + w2 * a2.w;
    *(float4*)&tile[qs2 * TILE_LD + lane * 4] = acc;
  }
  __syncthreads();
  {
    int qs2 = tid & 31;
    int cb = tid >> 5;
    size_t nout = (size_t)n0 + qs2;
    for (int it = 0; it < 32; ++it) {
      int cch = cb + it * 8;
      outg[((size_t)(b * CC + cch)) * NN + nout] = tile[qs2 * TILE_LD + cch];
    }
  }
}

extern "C" void kernel_launch(void* const* d_in, const int* in_sizes, int n_in,
                              void* d_out, int out_size, void* d_ws, size_t ws_size,
                              hipStream_t stream) {
  const float* q = (const float*)d_in[0];
  const float* k = (const float*)d_in[1];
  const float* v = (const float*)d_in[2];
  float* out = (float*)d_out;

  char* ws = (char*)d_ws;
  int* hdr = (int*)ws;
  float4* ksort = (float4*)(ws + 32768);
  int* kidx = (int*)(ws + 294912);
  int* qsort = (int*)(ws + 393216);
  int4* idx_o = (int4*)(ws + (1 << 20));
  float4* w_o = (float4*)(ws + (2 << 20));

  hipMemsetAsync(d_ws, 0, WS_ZERO_BYTES, stream);
  int nbuild = (BB * SS + BB * NN + 255) / 256;  // 320 blocks
  hipLaunchKernelGGL(count_kernel, dim3(nbuild), dim3(256), 0, stream, q, k, hdr);
  hipLaunchKernelGGL(prefix_kernel, dim3(1), dim3(64), 0, stream, hdr);
  hipLaunchKernelGGL(scatter_kernel, dim3(nbuild), dim3(256), 0, stream, q, k, hdr, ksort, kidx, qsort);
  hipLaunchKernelGGL(scan_kernel, dim3(2048), dim3(256), 0, stream, q, hdr, ksort, kidx, qsort, idx_o, w_o);
  hipLaunchKernelGGL(gather_kernel, dim3(2048), dim3(256), 0, stream, v, idx_o, w_o, out);
}